// Round 6
// baseline (153.560 us; speedup 1.0000x reference)
//
#include <hip/hip_runtime.h>

#define NLAYERS 4
#define BATCH   64
#define LEN1    256
#define LEN2    256
#define DIM     1024
#define BKK     32
#define NKT     (DIM / BKK)   // 32 K-tiles
#define PITCH   32            // halfs per LDS row (64 B) — DENSE: each wave's
                              // b128 access spans a contiguous 1024 B, banks
                              // perfectly balanced (structural minimum), no
                              // pad/swizzle needed at this row length.

typedef _Float16 f16x8 __attribute__((ext_vector_type(8)));
typedef float    f32x4 __attribute__((ext_vector_type(4)));

// ---------------------------------------------------------------------------
// Kernel 1: one 1024-thread block per (nl, b) — 16 waves, 4x4 wave grid, each
// wave owns a 64x64 output sub-tile.  A and B each read from global exactly
// once (536 MB logical).  f16 MFMA on unnormalized dots, fp32 sums-of-squares
// during staging, epilogue normalizes + masked max/mean -> F1.
// Double-buffered LDS (4-deep dwordx4 staging/thread — fits the 64-VGPR
// budget, NO spill), loads for tile k+1 in flight across tile k's MFMA,
// ONE barrier per K-tile.
// ---------------------------------------------------------------------------
__global__ __launch_bounds__(1024, 4)
void bs_main(const float* __restrict__ reps1, const float* __restrict__ reps2,
             const int* __restrict__ len1, const int* __restrict__ len2,
             float* __restrict__ feat) {
  __shared__ _Float16 Ah[2][LEN1 * PITCH];   // 2 x 16 KB
  __shared__ _Float16 Bh[2][LEN2 * PITCH];   // 2 x 16 KB
  __shared__ float ssq1[LEN1];
  __shared__ float ssq2[LEN2];
  __shared__ float rowp[LEN1][4];            // per-row max partials (by wn)
  __shared__ float colp[LEN2][4];            // per-col max partials (by wm)
  __shared__ float redbuf[32];

  const int bid = blockIdx.x;
  const int nl  = bid >> 6;
  const int bb  = bid & 63;
  const float* gA = reps1 + (size_t)bid * LEN1 * DIM;
  const float* gB = reps2 + (size_t)bid * LEN2 * DIM;

  const int tid  = threadIdx.x;
  const int lane = tid & 63;
  const int wid  = tid >> 6;     // 16 waves
  const int wm   = wid >> 2;     // 0..3  (M, 64 rows each)
  const int wn   = wid & 3;      // 0..3  (N, 64 cols each)
  const int li   = lane & 15;
  const int lh   = lane >> 4;

  f32x4 acc[4][4];
  #pragma unroll
  for (int a = 0; a < 4; ++a)
    #pragma unroll
    for (int c = 0; c < 4; ++c) acc[a][c] = 0.0f;

  float pssqA = 0.f, pssqB = 0.f;
  const int rS = tid >> 2;            // 0..255 : staged row (A and B)
  const int cS = (tid & 3) * 8;       // 8-float (16 B-of-halfs) chunk in row

  float4 ra[2], rb[2];

  auto issue_loads = [&](int kt) {
    const float4* a4 = (const float4*)(gA + (size_t)rS * DIM + kt * BKK + cS);
    ra[0] = a4[0];  ra[1] = a4[1];
    const float4* b4 = (const float4*)(gB + (size_t)rS * DIM + kt * BKK + cS);
    rb[0] = b4[0];  rb[1] = b4[1];
  };

  auto convert_write = [&](int buf) {
    const int idx = rS * PITCH + cS;   // dense 64 B rows, contiguous per wave
    {
      const float f0 = ra[0].x, f1 = ra[0].y, f2 = ra[0].z, f3 = ra[0].w;
      const float f4 = ra[1].x, f5 = ra[1].y, f6 = ra[1].z, f7 = ra[1].w;
      pssqA += f0*f0 + f1*f1 + f2*f2 + f3*f3 + f4*f4 + f5*f5 + f6*f6 + f7*f7;
      f16x8 hv;
      hv[0] = (_Float16)f0; hv[1] = (_Float16)f1; hv[2] = (_Float16)f2; hv[3] = (_Float16)f3;
      hv[4] = (_Float16)f4; hv[5] = (_Float16)f5; hv[6] = (_Float16)f6; hv[7] = (_Float16)f7;
      *(f16x8*)&Ah[buf][idx] = hv;
    }
    {
      const float f0 = rb[0].x, f1 = rb[0].y, f2 = rb[0].z, f3 = rb[0].w;
      const float f4 = rb[1].x, f5 = rb[1].y, f6 = rb[1].z, f7 = rb[1].w;
      pssqB += f0*f0 + f1*f1 + f2*f2 + f3*f3 + f4*f4 + f5*f5 + f6*f6 + f7*f7;
      f16x8 hv;
      hv[0] = (_Float16)f0; hv[1] = (_Float16)f1; hv[2] = (_Float16)f2; hv[3] = (_Float16)f3;
      hv[4] = (_Float16)f4; hv[5] = (_Float16)f5; hv[6] = (_Float16)f6; hv[7] = (_Float16)f7;
      *(f16x8*)&Bh[buf][idx] = hv;
    }
  };

  issue_loads(0);
  convert_write(0);
  __syncthreads();

  for (int kt = 0; kt < NKT; ++kt) {
    const int cur = kt & 1;
    const bool more = (kt + 1 < NKT);
    if (more) issue_loads(kt + 1);   // in flight across the MFMA phase

    const _Float16* AhC = Ah[cur];
    const _Float16* BhC = Bh[cur];
    f16x8 af[4];
    #pragma unroll
    for (int fm = 0; fm < 4; ++fm) {
      const int r = wm * 64 + fm * 16 + li;
      af[fm] = *(const f16x8*)&AhC[r * PITCH + lh * 8];
    }
    #pragma unroll
    for (int fn = 0; fn < 4; ++fn) {
      const int r = wn * 64 + fn * 16 + li;
      const f16x8 bf = *(const f16x8*)&BhC[r * PITCH + lh * 8];
      #pragma unroll
      for (int fm = 0; fm < 4; ++fm)
        acc[fm][fn] = __builtin_amdgcn_mfma_f32_16x16x32_f16(af[fm], bf, acc[fm][fn], 0, 0, 0);
    }

    if (more) convert_write(cur ^ 1);
    __syncthreads();
  }

  // ---- norms: deterministic 4-thread-per-row shuffle reduce, direct store
  pssqA += __shfl_xor(pssqA, 1, 64);
  pssqA += __shfl_xor(pssqA, 2, 64);
  pssqB += __shfl_xor(pssqB, 1, 64);
  pssqB += __shfl_xor(pssqB, 2, 64);
  if ((tid & 3) == 0) {
    ssq1[rS] = pssqA;
    ssq2[rS] = pssqB;
  }
  __syncthreads();
  if (tid < 256)       ssq1[tid] = 1.0f / sqrtf(ssq1[tid]);
  else if (tid < 512)  ssq2[tid - 256] = 1.0f / sqrtf(ssq2[tid - 256]);
  __syncthreads();

  const int n1 = len1[bb];
  const int n2 = len2[bb];

  float rn2v[4];
  bool  jv[4];
  #pragma unroll
  for (int fn = 0; fn < 4; ++fn) {
    const int j = wn * 64 + fn * 16 + li;
    rn2v[fn] = ssq2[j];
    jv[fn]   = (j < n2);
  }
  float rn1v[4][4];
  bool  iv[4][4];
  #pragma unroll
  for (int fm = 0; fm < 4; ++fm)
    #pragma unroll
    for (int rg = 0; rg < 4; ++rg) {
      const int i = wm * 64 + fm * 16 + lh * 4 + rg;
      rn1v[fm][rg] = ssq1[i];
      iv[fm][rg]   = (i < n1);
    }

  const float NEG = -3.402823466e38f;
  float rowm[4][4];
  float colm[4];
  #pragma unroll
  for (int fm = 0; fm < 4; ++fm)
    #pragma unroll
    for (int rg = 0; rg < 4; ++rg) rowm[fm][rg] = NEG;
  #pragma unroll
  for (int fn = 0; fn < 4; ++fn) colm[fn] = NEG;

  #pragma unroll
  for (int fm = 0; fm < 4; ++fm)
    #pragma unroll
    for (int fn = 0; fn < 4; ++fn)
      #pragma unroll
      for (int rg = 0; rg < 4; ++rg) {
        const float v = acc[fm][fn][rg] * rn1v[fm][rg] * rn2v[fn];
        if (jv[fn] && v > rowm[fm][rg]) rowm[fm][rg] = v;
        if (iv[fm][rg] && v > colm[fn]) colm[fn] = v;
      }

  // row maxima: reduce across li (lane bits 0..3)
  #pragma unroll
  for (int m = 1; m <= 8; m <<= 1)
    #pragma unroll
    for (int fm = 0; fm < 4; ++fm)
      #pragma unroll
      for (int rg = 0; rg < 4; ++rg) {
        const float o = __shfl_xor(rowm[fm][rg], m, 64);
        rowm[fm][rg] = fmaxf(rowm[fm][rg], o);
      }
  // col maxima: reduce across lh (lane bits 4..5)
  #pragma unroll
  for (int m = 16; m <= 32; m <<= 1)
    #pragma unroll
    for (int fn = 0; fn < 4; ++fn) {
      const float o = __shfl_xor(colm[fn], m, 64);
      colm[fn] = fmaxf(colm[fn], o);
    }

  if (li == 0)
    #pragma unroll
    for (int fm = 0; fm < 4; ++fm)
      #pragma unroll
      for (int rg = 0; rg < 4; ++rg)
        rowp[wm * 64 + fm * 16 + lh * 4 + rg][wn] = rowm[fm][rg];
  if (lh == 0)
    #pragma unroll
    for (int fn = 0; fn < 4; ++fn)
      colp[wn * 64 + fn * 16 + li][wm] = colm[fn];
  __syncthreads();

  float c1 = 0.f, c2 = 0.f;
  if (tid < 256) {
    const float rm = fmaxf(fmaxf(rowp[tid][0], rowp[tid][1]),
                           fmaxf(rowp[tid][2], rowp[tid][3]));
    if (tid < n1) c2 = rm;
    const float cm = fmaxf(fmaxf(colp[tid][0], colp[tid][1]),
                           fmaxf(colp[tid][2], colp[tid][3]));
    if (tid < n2) c1 = cm;
  }
  #pragma unroll
  for (int m = 1; m <= 32; m <<= 1) {
    c1 += __shfl_xor(c1, m, 64);
    c2 += __shfl_xor(c2, m, 64);
  }
  if (lane == 0) {
    redbuf[wid]      = c1;
    redbuf[16 + wid] = c2;
  }
  __syncthreads();
  if (tid == 0) {
    float s1s = 0.f, s2s = 0.f;
    #pragma unroll
    for (int i = 0; i < 16; ++i) { s1s += redbuf[i]; s2s += redbuf[16 + i]; }
    const float s1 = s1s / (float)n2;
    const float s2 = s2s / (float)n1;
    feat[bb * NLAYERS + nl] = 2.0f * s1 * s2 / (s1 + s2);
  }
}

// ---------------------------------------------------------------------------
// Kernel 2: BatchNorm1d (batch stats, biased var) + linear head -> out[b]
// ---------------------------------------------------------------------------
__global__ void bs_head(const float* __restrict__ feat, const float* __restrict__ w,
                        const float* __restrict__ bias, float* __restrict__ out) {
  __shared__ float lds[NLAYERS][BATCH];
  const int tid = threadIdx.x;
  const int nl  = tid >> 6;
  const int b   = tid & 63;

  const float x = feat[b * NLAYERS + nl];
  float s = x;
  #pragma unroll
  for (int m = 1; m <= 32; m <<= 1) s += __shfl_xor(s, m, 64);
  const float mean = s / 64.0f;
  const float d = x - mean;
  float v = d * d;
  #pragma unroll
  for (int m = 1; m <= 32; m <<= 1) v += __shfl_xor(v, m, 64);
  const float var = v / 64.0f;
  const float y = d / sqrtf(var + 1e-8f);

  lds[nl][b] = y * w[nl];
  __syncthreads();
  if (tid < 64)
    out[tid] = lds[0][tid] + lds[1][tid] + lds[2][tid] + lds[3][tid] + bias[0];
}

extern "C" void kernel_launch(void* const* d_in, const int* in_sizes, int n_in,
                              void* d_out, int out_size, void* d_ws, size_t ws_size,
                              hipStream_t stream) {
  const float* reps1 = (const float*)d_in[0];
  const float* reps2 = (const float*)d_in[1];
  const int*   len1  = (const int*)d_in[2];
  const int*   len2  = (const int*)d_in[3];
  const float* w     = (const float*)d_in[4];
  const float* bias  = (const float*)d_in[5];
  float* feat = (float*)d_ws;   // 256 floats

  bs_main<<<NLAYERS * BATCH, 1024, 0, stream>>>(reps1, reps2, len1, len2, feat);
  bs_head<<<1, 256, 0, stream>>>(feat, w, bias, (float*)d_out);
}

// Round 7
// 143.861 us; speedup vs baseline: 1.0674x; 1.0674x over previous
//
#include <hip/hip_runtime.h>

#define NLAYERS 4
#define BATCH   64
#define LEN1    256
#define LEN2    256
#define DIM     1024
#define BKK     32
#define NKT     (DIM / BKK)   // 32 K-tiles
#define PITCH   32            // halfs per LDS row (64 B), chunk-XOR-swizzled

typedef _Float16 f16x8 __attribute__((ext_vector_type(8)));
typedef float    f32x4 __attribute__((ext_vector_type(4)));

// LDS chunk swizzle: row r, 16B-chunk c (0..3)  ->  c ^ ((r>>1)&3).
// Quarter-wave analysis (16 lanes serviced together, b128):
//   read  (row=R0+li, chunk=lh^((li>>1)&3)): (li&1,(li>>1)&3) covers all 8
//         (parity,chunk) bank-groups x2 lanes  -> structural minimum, FREE
//   write (rows r0..r0+3, cq 0..3 swizzled):  each group exactly 2 lanes -> FREE
// Read-side conflicts sit on the MFMA critical path (16 waves contending);
// write-side hides under the vmcnt drain — R4/R6 bench deltas confirm.

// ---------------------------------------------------------------------------
// Kernel 1: one 1024-thread block per (nl, b) — 16 waves, 4x4 wave grid, each
// wave owns a 64x64 output sub-tile.  A and B each read from global exactly
// once.  f16 MFMA on unnormalized dots, fp32 sums-of-squares during staging,
// epilogue normalizes + masked max/mean -> F1.  Double-buffered LDS, loads
// for tile k+1 in flight across tile k's MFMA, ONE barrier per K-tile.
// ---------------------------------------------------------------------------
__global__ __launch_bounds__(1024, 4)
void bs_main(const float* __restrict__ reps1, const float* __restrict__ reps2,
             const int* __restrict__ len1, const int* __restrict__ len2,
             float* __restrict__ feat) {
  __shared__ _Float16 Ah[2][LEN1 * PITCH];   // 2 x 16 KB
  __shared__ _Float16 Bh[2][LEN2 * PITCH];   // 2 x 16 KB
  __shared__ float ssq1[LEN1];
  __shared__ float ssq2[LEN2];
  __shared__ float rowp[LEN1][4];            // per-row max partials (by wn)
  __shared__ float colp[LEN2][4];            // per-col max partials (by wm)
  __shared__ float redbuf[32];

  const int bid = blockIdx.x;
  const int nl  = bid >> 6;
  const int bb  = bid & 63;
  const float* gA = reps1 + (size_t)bid * LEN1 * DIM;
  const float* gB = reps2 + (size_t)bid * LEN2 * DIM;

  const int tid  = threadIdx.x;
  const int lane = tid & 63;
  const int wid  = tid >> 6;     // 16 waves
  const int wm   = wid >> 2;     // 0..3  (M, 64 rows each)
  const int wn   = wid & 3;      // 0..3  (N, 64 cols each)
  const int li   = lane & 15;
  const int lh   = lane >> 4;

  f32x4 acc[4][4];
  #pragma unroll
  for (int a = 0; a < 4; ++a)
    #pragma unroll
    for (int c = 0; c < 4; ++c) acc[a][c] = 0.0f;

  float pssqA = 0.f, pssqB = 0.f;
  const int rS = tid >> 2;            // 0..255 : staged row (A and B)
  const int cq = tid & 3;             // 0..3   : 16B chunk within row
  // swizzled write offset (halfs), row-invariant per thread
  const int wOff = rS * PITCH + (cq ^ ((rS >> 1) & 3)) * 8;

  float4 ra[2], rb[2];

  auto issue_loads = [&](int kt) {
    const float4* a4 = (const float4*)(gA + (size_t)rS * DIM + kt * BKK + cq * 8);
    ra[0] = a4[0];  ra[1] = a4[1];
    const float4* b4 = (const float4*)(gB + (size_t)rS * DIM + kt * BKK + cq * 8);
    rb[0] = b4[0];  rb[1] = b4[1];
  };

  auto convert_write = [&](int buf) {
    {
      const float f0 = ra[0].x, f1 = ra[0].y, f2 = ra[0].z, f3 = ra[0].w;
      const float f4 = ra[1].x, f5 = ra[1].y, f6 = ra[1].z, f7 = ra[1].w;
      pssqA += f0*f0 + f1*f1 + f2*f2 + f3*f3 + f4*f4 + f5*f5 + f6*f6 + f7*f7;
      f16x8 hv;
      hv[0] = (_Float16)f0; hv[1] = (_Float16)f1; hv[2] = (_Float16)f2; hv[3] = (_Float16)f3;
      hv[4] = (_Float16)f4; hv[5] = (_Float16)f5; hv[6] = (_Float16)f6; hv[7] = (_Float16)f7;
      *(f16x8*)&Ah[buf][wOff] = hv;
    }
    {
      const float f0 = rb[0].x, f1 = rb[0].y, f2 = rb[0].z, f3 = rb[0].w;
      const float f4 = rb[1].x, f5 = rb[1].y, f6 = rb[1].z, f7 = rb[1].w;
      pssqB += f0*f0 + f1*f1 + f2*f2 + f3*f3 + f4*f4 + f5*f5 + f6*f6 + f7*f7;
      f16x8 hv;
      hv[0] = (_Float16)f0; hv[1] = (_Float16)f1; hv[2] = (_Float16)f2; hv[3] = (_Float16)f3;
      hv[4] = (_Float16)f4; hv[5] = (_Float16)f5; hv[6] = (_Float16)f6; hv[7] = (_Float16)f7;
      *(f16x8*)&Bh[buf][wOff] = hv;
    }
  };

  issue_loads(0);
  convert_write(0);
  __syncthreads();

  for (int kt = 0; kt < NKT; ++kt) {
    const int cur = kt & 1;
    const bool more = (kt + 1 < NKT);
    if (more) issue_loads(kt + 1);   // in flight across the MFMA phase

    const _Float16* AhC = Ah[cur];
    const _Float16* BhC = Bh[cur];
    f16x8 af[4];
    #pragma unroll
    for (int fm = 0; fm < 4; ++fm) {
      const int r = wm * 64 + fm * 16 + li;
      af[fm] = *(const f16x8*)&AhC[r * PITCH + (lh ^ ((r >> 1) & 3)) * 8];
    }
    #pragma unroll
    for (int fn = 0; fn < 4; ++fn) {
      const int r = wn * 64 + fn * 16 + li;
      const f16x8 bf = *(const f16x8*)&BhC[r * PITCH + (lh ^ ((r >> 1) & 3)) * 8];
      #pragma unroll
      for (int fm = 0; fm < 4; ++fm)
        acc[fm][fn] = __builtin_amdgcn_mfma_f32_16x16x32_f16(af[fm], bf, acc[fm][fn], 0, 0, 0);
    }

    if (more) convert_write(cur ^ 1);
    __syncthreads();
  }

  // ---- norms: deterministic 4-thread-per-row shuffle reduce, direct store
  pssqA += __shfl_xor(pssqA, 1, 64);
  pssqA += __shfl_xor(pssqA, 2, 64);
  pssqB += __shfl_xor(pssqB, 1, 64);
  pssqB += __shfl_xor(pssqB, 2, 64);
  if (cq == 0) {
    ssq1[rS] = pssqA;
    ssq2[rS] = pssqB;
  }
  __syncthreads();
  if (tid < 256)       ssq1[tid] = 1.0f / sqrtf(ssq1[tid]);
  else if (tid < 512)  ssq2[tid - 256] = 1.0f / sqrtf(ssq2[tid - 256]);
  __syncthreads();

  const int n1 = len1[bb];
  const int n2 = len2[bb];

  float rn2v[4];
  bool  jv[4];
  #pragma unroll
  for (int fn = 0; fn < 4; ++fn) {
    const int j = wn * 64 + fn * 16 + li;
    rn2v[fn] = ssq2[j];
    jv[fn]   = (j < n2);
  }
  float rn1v[4][4];
  bool  iv[4][4];
  #pragma unroll
  for (int fm = 0; fm < 4; ++fm)
    #pragma unroll
    for (int rg = 0; rg < 4; ++rg) {
      const int i = wm * 64 + fm * 16 + lh * 4 + rg;
      rn1v[fm][rg] = ssq1[i];
      iv[fm][rg]   = (i < n1);
    }

  const float NEG = -3.402823466e38f;
  float rowm[4][4];
  float colm[4];
  #pragma unroll
  for (int fm = 0; fm < 4; ++fm)
    #pragma unroll
    for (int rg = 0; rg < 4; ++rg) rowm[fm][rg] = NEG;
  #pragma unroll
  for (int fn = 0; fn < 4; ++fn) colm[fn] = NEG;

  #pragma unroll
  for (int fm = 0; fm < 4; ++fm)
    #pragma unroll
    for (int fn = 0; fn < 4; ++fn)
      #pragma unroll
      for (int rg = 0; rg < 4; ++rg) {
        const float v = acc[fm][fn][rg] * rn1v[fm][rg] * rn2v[fn];
        if (jv[fn] && v > rowm[fm][rg]) rowm[fm][rg] = v;
        if (iv[fm][rg] && v > colm[fn]) colm[fn] = v;
      }

  // row maxima: reduce across li (lane bits 0..3)
  #pragma unroll
  for (int m = 1; m <= 8; m <<= 1)
    #pragma unroll
    for (int fm = 0; fm < 4; ++fm)
      #pragma unroll
      for (int rg = 0; rg < 4; ++rg) {
        const float o = __shfl_xor(rowm[fm][rg], m, 64);
        rowm[fm][rg] = fmaxf(rowm[fm][rg], o);
      }
  // col maxima: reduce across lh (lane bits 4..5)
  #pragma unroll
  for (int m = 16; m <= 32; m <<= 1)
    #pragma unroll
    for (int fn = 0; fn < 4; ++fn) {
      const float o = __shfl_xor(colm[fn], m, 64);
      colm[fn] = fmaxf(colm[fn], o);
    }

  if (li == 0)
    #pragma unroll
    for (int fm = 0; fm < 4; ++fm)
      #pragma unroll
      for (int rg = 0; rg < 4; ++rg)
        rowp[wm * 64 + fm * 16 + lh * 4 + rg][wn] = rowm[fm][rg];
  if (lh == 0)
    #pragma unroll
    for (int fn = 0; fn < 4; ++fn)
      colp[wn * 64 + fn * 16 + li][wm] = colm[fn];
  __syncthreads();

  float c1 = 0.f, c2 = 0.f;
  if (tid < 256) {
    const float rm = fmaxf(fmaxf(rowp[tid][0], rowp[tid][1]),
                           fmaxf(rowp[tid][2], rowp[tid][3]));
    if (tid < n1) c2 = rm;
    const float cm = fmaxf(fmaxf(colp[tid][0], colp[tid][1]),
                           fmaxf(colp[tid][2], colp[tid][3]));
    if (tid < n2) c1 = cm;
  }
  #pragma unroll
  for (int m = 1; m <= 32; m <<= 1) {
    c1 += __shfl_xor(c1, m, 64);
    c2 += __shfl_xor(c2, m, 64);
  }
  if (lane == 0) {
    redbuf[wid]      = c1;
    redbuf[16 + wid] = c2;
  }
  __syncthreads();
  if (tid == 0) {
    float s1s = 0.f, s2s = 0.f;
    #pragma unroll
    for (int i = 0; i < 16; ++i) { s1s += redbuf[i]; s2s += redbuf[16 + i]; }
    const float s1 = s1s / (float)n2;
    const float s2 = s2s / (float)n1;
    feat[bb * NLAYERS + nl] = 2.0f * s1 * s2 / (s1 + s2);
  }
}

// ---------------------------------------------------------------------------
// Kernel 2: BatchNorm1d (batch stats, biased var) + linear head -> out[b]
// ---------------------------------------------------------------------------
__global__ void bs_head(const float* __restrict__ feat, const float* __restrict__ w,
                        const float* __restrict__ bias, float* __restrict__ out) {
  __shared__ float lds[NLAYERS][BATCH];
  const int tid = threadIdx.x;
  const int nl  = tid >> 6;
  const int b   = tid & 63;

  const float x = feat[b * NLAYERS + nl];
  float s = x;
  #pragma unroll
  for (int m = 1; m <= 32; m <<= 1) s += __shfl_xor(s, m, 64);
  const float mean = s / 64.0f;
  const float d = x - mean;
  float v = d * d;
  #pragma unroll
  for (int m = 1; m <= 32; m <<= 1) v += __shfl_xor(v, m, 64);
  const float var = v / 64.0f;
  const float y = d / sqrtf(var + 1e-8f);

  lds[nl][b] = y * w[nl];
  __syncthreads();
  if (tid < 64)
    out[tid] = lds[0][tid] + lds[1][tid] + lds[2][tid] + lds[3][tid] + bias[0];
}

extern "C" void kernel_launch(void* const* d_in, const int* in_sizes, int n_in,
                              void* d_out, int out_size, void* d_ws, size_t ws_size,
                              hipStream_t stream) {
  const float* reps1 = (const float*)d_in[0];
  const float* reps2 = (const float*)d_in[1];
  const int*   len1  = (const int*)d_in[2];
  const int*   len2  = (const int*)d_in[3];
  const float* w     = (const float*)d_in[4];
  const float* bias  = (const float*)d_in[5];
  float* feat = (float*)d_ws;   // 256 floats

  bs_main<<<NLAYERS * BATCH, 1024, 0, stream>>>(reps1, reps2, len1, len2, feat);
  bs_head<<<1, 256, 0, stream>>>(feat, w, bias, (float*)d_out);
}

// Round 8
// 126.850 us; speedup vs baseline: 1.2106x; 1.1341x over previous
//
#include <hip/hip_runtime.h>

#define NLAYERS 4
#define BATCH   64
#define LEN1    256
#define LEN2    256
#define DIM     1024
#define BKK     64
#define NKT     (DIM / BKK)   // 16 K-tiles
#define PITCH   64            // halfs per LDS row (128 B) = 8 chunks of 16 B

// chunk swizzle: c' = c ^ SWZ(row).  Quarter-wave bank walk:
//  reads (16 consecutive rows, fixed c): SWZ takes 8 values x2 -> 2-way, free
//  writes (4 rows x 4 chunks of one half): bit2 of SWZ alternates with row
//    parity, pushing half the writes into the other 4-chunk group -> 2-way.
//  (a plain r&7 XOR leaves writes 4-way: half-tile chunk span stays in one
//   group when (r&7)<4 — this variant fixes that.)
#define SWZ(r) ((((r) & 1) << 2) | (((r) >> 1) & 3))

typedef _Float16 f16x8 __attribute__((ext_vector_type(8)));
typedef float    f32x4 __attribute__((ext_vector_type(4)));

// ---------------------------------------------------------------------------
// Kernel 1: one 1024-thread block per (nl, b) — 16 waves, 4x4 wave grid, each
// wave owns a 64x64 output sub-tile.  A and B each read from global exactly
// once.  f16 MFMA on unnormalized dots, fp32 sums-of-squares during staging,
// epilogue normalizes + masked max/mean -> F1.
// K-tile = 64, processed as two half-phases:
//   {issue half0(k+1); MFMA ks=0; cvt+write half0;
//    issue half1(k+1); MFMA ks=1; cvt+write half1; barrier}
// -> 16 barriers total, peak staging = 16 VGPRs (no spill), double-buffered.
// ---------------------------------------------------------------------------
__global__ __launch_bounds__(1024, 4)
void bs_main(const float* __restrict__ reps1, const float* __restrict__ reps2,
             const int* __restrict__ len1, const int* __restrict__ len2,
             float* __restrict__ feat) {
  __shared__ _Float16 Ah[2][LEN1 * PITCH];   // 2 x 32 KB
  __shared__ _Float16 Bh[2][LEN2 * PITCH];   // 2 x 32 KB
  __shared__ float ssq1[LEN1];
  __shared__ float ssq2[LEN2];
  __shared__ float rowp[LEN1][4];            // per-row max partials (by wn)
  __shared__ float colp[LEN2][4];            // per-col max partials (by wm)
  __shared__ float redbuf[32];

  const int bid = blockIdx.x;
  const int nl  = bid >> 6;
  const int bb  = bid & 63;
  const float* gA = reps1 + (size_t)bid * LEN1 * DIM;
  const float* gB = reps2 + (size_t)bid * LEN2 * DIM;

  const int tid  = threadIdx.x;
  const int lane = tid & 63;
  const int wid  = tid >> 6;     // 16 waves
  const int wm   = wid >> 2;     // 0..3  (M, 64 rows each)
  const int wn   = wid & 3;      // 0..3  (N, 64 cols each)
  const int li   = lane & 15;
  const int lh   = lane >> 4;

  f32x4 acc[4][4];
  #pragma unroll
  for (int a = 0; a < 4; ++a)
    #pragma unroll
    for (int c = 0; c < 4; ++c) acc[a][c] = 0.0f;

  float pssqA = 0.f, pssqB = 0.f;
  const int rS = tid >> 2;            // 0..255 : staged row (A and B)
  const int cq = tid & 3;             // 0..3   : 8-float chunk within half

  float4 ra[2], rb[2];

  // issue 8 floats of A + 8 of B for half h of tile kt
  auto issue_half = [&](int kt, int h) {
    const int col = kt * BKK + h * 32 + cq * 8;
    const float4* a4 = (const float4*)(gA + (size_t)rS * DIM + col);
    ra[0] = a4[0];  ra[1] = a4[1];
    const float4* b4 = (const float4*)(gB + (size_t)rS * DIM + col);
    rb[0] = b4[0];  rb[1] = b4[1];
  };

  // swizzled write offset for half h (16B chunk index h*4+cq)
  auto cvt_write = [&](int buf, int h) {
    const int off = rS * PITCH + (((h * 4 + cq) ^ SWZ(rS)) << 3);
    {
      const float f0 = ra[0].x, f1 = ra[0].y, f2 = ra[0].z, f3 = ra[0].w;
      const float f4 = ra[1].x, f5 = ra[1].y, f6 = ra[1].z, f7 = ra[1].w;
      pssqA += f0*f0 + f1*f1 + f2*f2 + f3*f3 + f4*f4 + f5*f5 + f6*f6 + f7*f7;
      f16x8 hv;
      hv[0] = (_Float16)f0; hv[1] = (_Float16)f1; hv[2] = (_Float16)f2; hv[3] = (_Float16)f3;
      hv[4] = (_Float16)f4; hv[5] = (_Float16)f5; hv[6] = (_Float16)f6; hv[7] = (_Float16)f7;
      *(f16x8*)&Ah[buf][off] = hv;
    }
    {
      const float f0 = rb[0].x, f1 = rb[0].y, f2 = rb[0].z, f3 = rb[0].w;
      const float f4 = rb[1].x, f5 = rb[1].y, f6 = rb[1].z, f7 = rb[1].w;
      pssqB += f0*f0 + f1*f1 + f2*f2 + f3*f3 + f4*f4 + f5*f5 + f6*f6 + f7*f7;
      f16x8 hv;
      hv[0] = (_Float16)f0; hv[1] = (_Float16)f1; hv[2] = (_Float16)f2; hv[3] = (_Float16)f3;
      hv[4] = (_Float16)f4; hv[5] = (_Float16)f5; hv[6] = (_Float16)f6; hv[7] = (_Float16)f7;
      *(f16x8*)&Bh[buf][off] = hv;
    }
  };

  // prologue: stage tile 0 into buffer 0 (sequential halves, 16 regs peak)
  issue_half(0, 0);  cvt_write(0, 0);
  issue_half(0, 1);  cvt_write(0, 1);
  __syncthreads();

  for (int kt = 0; kt < NKT; ++kt) {
    const int cur  = kt & 1;
    const int nxt  = cur ^ 1;
    const bool more = (kt + 1 < NKT);

    const _Float16* AhC = Ah[cur];
    const _Float16* BhC = Bh[cur];

    if (more) issue_half(kt + 1, 0);
    // ---- MFMA ks = 0 (chunks 0..3 via lh)
    {
      f16x8 af[4];
      #pragma unroll
      for (int fm = 0; fm < 4; ++fm) {
        const int r = wm * 64 + fm * 16 + li;
        af[fm] = *(const f16x8*)&AhC[r * PITCH + ((lh ^ SWZ(r)) << 3)];
      }
      #pragma unroll
      for (int fn = 0; fn < 4; ++fn) {
        const int r = wn * 64 + fn * 16 + li;
        const f16x8 bf = *(const f16x8*)&BhC[r * PITCH + ((lh ^ SWZ(r)) << 3)];
        #pragma unroll
        for (int fm = 0; fm < 4; ++fm)
          acc[fm][fn] = __builtin_amdgcn_mfma_f32_16x16x32_f16(af[fm], bf, acc[fm][fn], 0, 0, 0);
      }
    }
    if (more) cvt_write(nxt, 0);

    if (more) issue_half(kt + 1, 1);
    // ---- MFMA ks = 1 (chunks 4..7 via lh)
    {
      f16x8 af[4];
      #pragma unroll
      for (int fm = 0; fm < 4; ++fm) {
        const int r = wm * 64 + fm * 16 + li;
        af[fm] = *(const f16x8*)&AhC[r * PITCH + (((4 + lh) ^ SWZ(r)) << 3)];
      }
      #pragma unroll
      for (int fn = 0; fn < 4; ++fn) {
        const int r = wn * 64 + fn * 16 + li;
        const f16x8 bf = *(const f16x8*)&BhC[r * PITCH + (((4 + lh) ^ SWZ(r)) << 3)];
        #pragma unroll
        for (int fm = 0; fm < 4; ++fm)
          acc[fm][fn] = __builtin_amdgcn_mfma_f32_16x16x32_f16(af[fm], bf, acc[fm][fn], 0, 0, 0);
      }
    }
    if (more) cvt_write(nxt, 1);

    __syncthreads();
  }

  // ---- norms: deterministic 4-thread-per-row shuffle reduce, direct store
  pssqA += __shfl_xor(pssqA, 1, 64);
  pssqA += __shfl_xor(pssqA, 2, 64);
  pssqB += __shfl_xor(pssqB, 1, 64);
  pssqB += __shfl_xor(pssqB, 2, 64);
  if (cq == 0) {
    ssq1[rS] = pssqA;
    ssq2[rS] = pssqB;
  }
  __syncthreads();
  if (tid < 256)       ssq1[tid] = 1.0f / sqrtf(ssq1[tid]);
  else if (tid < 512)  ssq2[tid - 256] = 1.0f / sqrtf(ssq2[tid - 256]);
  __syncthreads();

  const int n1 = len1[bb];
  const int n2 = len2[bb];

  float rn2v[4];
  bool  jv[4];
  #pragma unroll
  for (int fn = 0; fn < 4; ++fn) {
    const int j = wn * 64 + fn * 16 + li;
    rn2v[fn] = ssq2[j];
    jv[fn]   = (j < n2);
  }
  float rn1v[4][4];
  bool  iv[4][4];
  #pragma unroll
  for (int fm = 0; fm < 4; ++fm)
    #pragma unroll
    for (int rg = 0; rg < 4; ++rg) {
      const int i = wm * 64 + fm * 16 + lh * 4 + rg;
      rn1v[fm][rg] = ssq1[i];
      iv[fm][rg]   = (i < n1);
    }

  const float NEG = -3.402823466e38f;
  float rowm[4][4];
  float colm[4];
  #pragma unroll
  for (int fm = 0; fm < 4; ++fm)
    #pragma unroll
    for (int rg = 0; rg < 4; ++rg) rowm[fm][rg] = NEG;
  #pragma unroll
  for (int fn = 0; fn < 4; ++fn) colm[fn] = NEG;

  #pragma unroll
  for (int fm = 0; fm < 4; ++fm)
    #pragma unroll
    for (int fn = 0; fn < 4; ++fn)
      #pragma unroll
      for (int rg = 0; rg < 4; ++rg) {
        const float v = acc[fm][fn][rg] * rn1v[fm][rg] * rn2v[fn];
        if (jv[fn] && v > rowm[fm][rg]) rowm[fm][rg] = v;
        if (iv[fm][rg] && v > colm[fn]) colm[fn] = v;
      }

  // row maxima: reduce across li (lane bits 0..3)
  #pragma unroll
  for (int m = 1; m <= 8; m <<= 1)
    #pragma unroll
    for (int fm = 0; fm < 4; ++fm)
      #pragma unroll
      for (int rg = 0; rg < 4; ++rg) {
        const float o = __shfl_xor(rowm[fm][rg], m, 64);
        rowm[fm][rg] = fmaxf(rowm[fm][rg], o);
      }
  // col maxima: reduce across lh (lane bits 4..5)
  #pragma unroll
  for (int m = 16; m <= 32; m <<= 1)
    #pragma unroll
    for (int fn = 0; fn < 4; ++fn) {
      const float o = __shfl_xor(colm[fn], m, 64);
      colm[fn] = fmaxf(colm[fn], o);
    }

  if (li == 0)
    #pragma unroll
    for (int fm = 0; fm < 4; ++fm)
      #pragma unroll
      for (int rg = 0; rg < 4; ++rg)
        rowp[wm * 64 + fm * 16 + lh * 4 + rg][wn] = rowm[fm][rg];
  if (lh == 0)
    #pragma unroll
    for (int fn = 0; fn < 4; ++fn)
      colp[wn * 64 + fn * 16 + li][wm] = colm[fn];
  __syncthreads();

  float c1 = 0.f, c2 = 0.f;
  if (tid < 256) {
    const float rm = fmaxf(fmaxf(rowp[tid][0], rowp[tid][1]),
                           fmaxf(rowp[tid][2], rowp[tid][3]));
    if (tid < n1) c2 = rm;
    const float cm = fmaxf(fmaxf(colp[tid][0], colp[tid][1]),
                           fmaxf(colp[tid][2], colp[tid][3]));
    if (tid < n2) c1 = cm;
  }
  #pragma unroll
  for (int m = 1; m <= 32; m <<= 1) {
    c1 += __shfl_xor(c1, m, 64);
    c2 += __shfl_xor(c2, m, 64);
  }
  if (lane == 0) {
    redbuf[wid]      = c1;
    redbuf[16 + wid] = c2;
  }
  __syncthreads();
  if (tid == 0) {
    float s1s = 0.f, s2s = 0.f;
    #pragma unroll
    for (int i = 0; i < 16; ++i) { s1s += redbuf[i]; s2s += redbuf[16 + i]; }
    const float s1 = s1s / (float)n2;
    const float s2 = s2s / (float)n1;
    feat[bb * NLAYERS + nl] = 2.0f * s1 * s2 / (s1 + s2);
  }
}

// ---------------------------------------------------------------------------
// Kernel 2: BatchNorm1d (batch stats, biased var) + linear head -> out[b]
// ---------------------------------------------------------------------------
__global__ void bs_head(const float* __restrict__ feat, const float* __restrict__ w,
                        const float* __restrict__ bias, float* __restrict__ out) {
  __shared__ float lds[NLAYERS][BATCH];
  const int tid = threadIdx.x;
  const int nl  = tid >> 6;
  const int b   = tid & 63;

  const float x = feat[b * NLAYERS + nl];
  float s = x;
  #pragma unroll
  for (int m = 1; m <= 32; m <<= 1) s += __shfl_xor(s, m, 64);
  const float mean = s / 64.0f;
  const float d = x - mean;
  float v = d * d;
  #pragma unroll
  for (int m = 1; m <= 32; m <<= 1) v += __shfl_xor(v, m, 64);
  const float var = v / 64.0f;
  const float y = d / sqrtf(var + 1e-8f);

  lds[nl][b] = y * w[nl];
  __syncthreads();
  if (tid < 64)
    out[tid] = lds[0][tid] + lds[1][tid] + lds[2][tid] + lds[3][tid] + bias[0];
}

extern "C" void kernel_launch(void* const* d_in, const int* in_sizes, int n_in,
                              void* d_out, int out_size, void* d_ws, size_t ws_size,
                              hipStream_t stream) {
  const float* reps1 = (const float*)d_in[0];
  const float* reps2 = (const float*)d_in[1];
  const int*   len1  = (const int*)d_in[2];
  const int*   len2  = (const int*)d_in[3];
  const float* w     = (const float*)d_in[4];
  const float* bias  = (const float*)d_in[5];
  float* feat = (float*)d_ws;   // 256 floats

  bs_main<<<NLAYERS * BATCH, 1024, 0, stream>>>(reps1, reps2, len1, len2, feat);
  bs_head<<<1, 256, 0, stream>>>(feat, w, bias, (float*)d_out);
}

// Round 9
// 111.734 us; speedup vs baseline: 1.3743x; 1.1353x over previous
//
#include <hip/hip_runtime.h>

#define NLAYERS 4
#define BATCH   64
#define LEN1    256
#define LEN2    256
#define DIM     1024
#define BKK     32
#define NKT     (DIM / BKK)   // 32 K-tiles

typedef _Float16 f16x8 __attribute__((ext_vector_type(8)));
typedef float    f32x4 __attribute__((ext_vector_type(4)));

typedef __attribute__((address_space(1))) const void gas_void;
typedef __attribute__((address_space(3))) void       las_void;

__device__ __forceinline__ void dma16(const float* g, float* l) {
  // 16-byte global->LDS DMA (no VGPR round trip)
  __builtin_amdgcn_global_load_lds((gas_void*)g, (las_void*)l, 16, 0, 0);
}

__device__ __forceinline__ void block_bar() {
  asm volatile("" ::: "memory");
  __builtin_amdgcn_s_barrier();
  asm volatile("" ::: "memory");
}

#define WAITVM(N) asm volatile("s_waitcnt vmcnt(" #N ")" ::: "memory")

// ---------------------------------------------------------------------------
// Kernel 1: one 1024-thread block per (nl, b); 16 waves, 4x4 wave grid, each
// wave owns a 64x64 output sub-tile.  A and B each read from global once.
//
// NEW STRUCTURE: fp32 tiles staged straight into LDS via global_load_lds
// (no staging VGPRs, no cvt/ds_write chain).  fp32->f16 conversion happens at
// fragment-read time.  Raw s_barrier + counted vmcnt(4) keep next-tile DMAs
// in flight across the whole compute phase (no compiler vmcnt(0) drain).
//
// LDS layout (per buffer, per matrix): row-major [256][32] fp32, 8 chunks of
// 16 B per row, LINEAR (DMA requirement).  The DMA's GLOBAL source column is
// pre-swizzled: LDS(row, ch) holds global chunk ch ^ (row&7); readers apply
// the same involution -> conflict-free ds_reads, linear DMA writes.
//
// Sync per tile (2 raw barriers):
//   DMA(k+1 -> nxt) ; vmcnt(4) [own k done] ; BAR-B [everyone's k visible]
//   compute(k from cur)                     ; BAR-A [reads done before k+2
//                                              DMA may overwrite cur]
// ---------------------------------------------------------------------------
__global__ __launch_bounds__(1024, 4)
void bs_main(const float* __restrict__ reps1, const float* __restrict__ reps2,
             const int* __restrict__ len1, const int* __restrict__ len2,
             float* __restrict__ feat) {
  __shared__ float Af[2][LEN1 * BKK];   // 2 x 32 KB
  __shared__ float Bf[2][LEN2 * BKK];   // 2 x 32 KB
  __shared__ float ssq1[LEN1];
  __shared__ float ssq2[LEN2];
  __shared__ float rowp[LEN1][4];       // per-row max partials (by wn)
  __shared__ float colp[LEN2][4];       // per-col max partials (by wm)
  __shared__ float redbuf[32];

  const int bid = blockIdx.x;
  const int nl  = bid >> 6;
  const int bb  = bid & 63;
  const float* gA = reps1 + (size_t)bid * LEN1 * DIM;
  const float* gB = reps2 + (size_t)bid * LEN2 * DIM;

  const int tid  = threadIdx.x;
  const int lane = tid & 63;
  const int wid  = tid >> 6;     // 16 waves
  const int wm   = wid >> 2;     // 0..3  (M, 64 rows each)
  const int wn   = wid & 3;      // 0..3  (N, 64 cols each)
  const int li   = lane & 15;
  const int lh   = lane >> 4;

  f32x4 acc[4][4];
  #pragma unroll
  for (int a = 0; a < 4; ++a)
    #pragma unroll
    for (int c = 0; c < 4; ++c) acc[a][c] = 0.0f;

  // staging geometry: slot s (0..2047) = 16B chunk; row = s>>3, ch = s&7.
  // thread t owns slots t and t+1024 of both A and B.
  const int r0  = tid >> 3;            // row of slot j=0 (j=1: +128)
  const int ch0 = tid & 7;
  const int sc0 = (ch0 ^ (r0 & 7)) << 2;          // swizzled src col (floats)
  const int sc1 = (ch0 ^ ((r0 + 128) & 7)) << 2;

  float pssqA0 = 0.f, pssqA1 = 0.f, pssqB0 = 0.f, pssqB1 = 0.f;

  auto stage = [&](int kt, int buf) {
    const int col = kt * BKK;
    dma16(gA + (size_t)r0 * DIM + col + sc0,          &Af[buf][tid * 4]);
    dma16(gB + (size_t)r0 * DIM + col + sc0,          &Bf[buf][tid * 4]);
    dma16(gA + (size_t)(r0 + 128) * DIM + col + sc1,  &Af[buf][(tid + 1024) * 4]);
    dma16(gB + (size_t)(r0 + 128) * DIM + col + sc1,  &Bf[buf][(tid + 1024) * 4]);
  };

  stage(0, 0);   // prologue: tile 0 -> buffer 0 (4 DMAs in flight)

  #pragma unroll 1
  for (int kt = 0; kt < NKT; ++kt) {
    const int cur = kt & 1;
    if (kt + 1 < NKT) {
      stage(kt + 1, cur ^ 1);   // in flight across this whole tile's compute
      WAITVM(4);                // own tile-k DMAs done; k+1's stay in flight
    } else {
      WAITVM(0);
    }
    block_bar();                // BAR-B: everyone's tile-k data visible

    const float* Ac = Af[cur];
    const float* Bc = Bf[cur];

    // ---- ssq readback: each thread re-reads its own staged 64 B (linear)
    {
      const float4 a0 = *(const float4*)&Ac[tid * 4];
      const float4 a1 = *(const float4*)&Ac[(tid + 1024) * 4];
      const float4 b0 = *(const float4*)&Bc[tid * 4];
      const float4 b1 = *(const float4*)&Bc[(tid + 1024) * 4];
      pssqA0 += a0.x*a0.x + a0.y*a0.y + a0.z*a0.z + a0.w*a0.w;
      pssqA1 += a1.x*a1.x + a1.y*a1.y + a1.z*a1.z + a1.w*a1.w;
      pssqB0 += b0.x*b0.x + b0.y*b0.y + b0.z*b0.z + b0.w*b0.w;
      pssqB1 += b1.x*b1.x + b1.y*b1.y + b1.z*b1.z + b1.w*b1.w;
    }

    // ---- fragments: read fp32 (swizzled chunk), convert, MFMA
    f16x8 af[4];
    #pragma unroll
    for (int fm = 0; fm < 4; ++fm) {
      const int r = wm * 64 + fm * 16 + li;
      const float4 x0 = *(const float4*)&Ac[r * BKK + ((((lh << 1)    ) ^ (r & 7)) << 2)];
      const float4 x1 = *(const float4*)&Ac[r * BKK + ((((lh << 1) | 1) ^ (r & 7)) << 2)];
      f16x8 h;
      h[0] = (_Float16)x0.x; h[1] = (_Float16)x0.y; h[2] = (_Float16)x0.z; h[3] = (_Float16)x0.w;
      h[4] = (_Float16)x1.x; h[5] = (_Float16)x1.y; h[6] = (_Float16)x1.z; h[7] = (_Float16)x1.w;
      af[fm] = h;
    }
    #pragma unroll
    for (int fn = 0; fn < 4; ++fn) {
      const int r = wn * 64 + fn * 16 + li;
      const float4 y0 = *(const float4*)&Bc[r * BKK + ((((lh << 1)    ) ^ (r & 7)) << 2)];
      const float4 y1 = *(const float4*)&Bc[r * BKK + ((((lh << 1) | 1) ^ (r & 7)) << 2)];
      f16x8 bh;
      bh[0] = (_Float16)y0.x; bh[1] = (_Float16)y0.y; bh[2] = (_Float16)y0.z; bh[3] = (_Float16)y0.w;
      bh[4] = (_Float16)y1.x; bh[5] = (_Float16)y1.y; bh[6] = (_Float16)y1.z; bh[7] = (_Float16)y1.w;
      #pragma unroll
      for (int fm = 0; fm < 4; ++fm)
        acc[fm][fn] = __builtin_amdgcn_mfma_f32_16x16x32_f16(af[fm], bh, acc[fm][fn], 0, 0, 0);
    }

    block_bar();                // BAR-A: reads of cur done before next DMA
  }

  // ---- norms: reduce the 8 chunk-threads of each row (lane bits 0..2)
  #pragma unroll
  for (int m = 1; m <= 4; m <<= 1) {
    pssqA0 += __shfl_xor(pssqA0, m, 64);
    pssqA1 += __shfl_xor(pssqA1, m, 64);
    pssqB0 += __shfl_xor(pssqB0, m, 64);
    pssqB1 += __shfl_xor(pssqB1, m, 64);
  }
  if ((lane & 7) == 0) {
    ssq1[r0] = pssqA0;  ssq1[r0 + 128] = pssqA1;
    ssq2[r0] = pssqB0;  ssq2[r0 + 128] = pssqB1;
  }
  __syncthreads();
  if (tid < 256)       ssq1[tid] = 1.0f / sqrtf(ssq1[tid]);
  else if (tid < 512)  ssq2[tid - 256] = 1.0f / sqrtf(ssq2[tid - 256]);
  __syncthreads();

  const int n1 = len1[bb];
  const int n2 = len2[bb];

  float rn2v[4];
  bool  jv[4];
  #pragma unroll
  for (int fn = 0; fn < 4; ++fn) {
    const int j = wn * 64 + fn * 16 + li;
    rn2v[fn] = ssq2[j];
    jv[fn]   = (j < n2);
  }
  float rn1v[4][4];
  bool  iv[4][4];
  #pragma unroll
  for (int fm = 0; fm < 4; ++fm)
    #pragma unroll
    for (int rg = 0; rg < 4; ++rg) {
      const int i = wm * 64 + fm * 16 + lh * 4 + rg;
      rn1v[fm][rg] = ssq1[i];
      iv[fm][rg]   = (i < n1);
    }

  const float NEG = -3.402823466e38f;
  float rowm[4][4];
  float colm[4];
  #pragma unroll
  for (int fm = 0; fm < 4; ++fm)
    #pragma unroll
    for (int rg = 0; rg < 4; ++rg) rowm[fm][rg] = NEG;
  #pragma unroll
  for (int fn = 0; fn < 4; ++fn) colm[fn] = NEG;

  #pragma unroll
  for (int fm = 0; fm < 4; ++fm)
    #pragma unroll
    for (int fn = 0; fn < 4; ++fn)
      #pragma unroll
      for (int rg = 0; rg < 4; ++rg) {
        const float v = acc[fm][fn][rg] * rn1v[fm][rg] * rn2v[fn];
        if (jv[fn] && v > rowm[fm][rg]) rowm[fm][rg] = v;
        if (iv[fm][rg] && v > colm[fn]) colm[fn] = v;
      }

  // row maxima: reduce across li (lane bits 0..3)
  #pragma unroll
  for (int m = 1; m <= 8; m <<= 1)
    #pragma unroll
    for (int fm = 0; fm < 4; ++fm)
      #pragma unroll
      for (int rg = 0; rg < 4; ++rg) {
        const float o = __shfl_xor(rowm[fm][rg], m, 64);
        rowm[fm][rg] = fmaxf(rowm[fm][rg], o);
      }
  // col maxima: reduce across lh (lane bits 4..5)
  #pragma unroll
  for (int m = 16; m <= 32; m <<= 1)
    #pragma unroll
    for (int fn = 0; fn < 4; ++fn) {
      const float o = __shfl_xor(colm[fn], m, 64);
      colm[fn] = fmaxf(colm[fn], o);
    }

  if (li == 0)
    #pragma unroll
    for (int fm = 0; fm < 4; ++fm)
      #pragma unroll
      for (int rg = 0; rg < 4; ++rg)
        rowp[wm * 64 + fm * 16 + lh * 4 + rg][wn] = rowm[fm][rg];
  if (lh == 0)
    #pragma unroll
    for (int fn = 0; fn < 4; ++fn)
      colp[wn * 64 + fn * 16 + li][wm] = colm[fn];
  __syncthreads();

  float c1 = 0.f, c2 = 0.f;
  if (tid < 256) {
    const float rm = fmaxf(fmaxf(rowp[tid][0], rowp[tid][1]),
                           fmaxf(rowp[tid][2], rowp[tid][3]));
    if (tid < n1) c2 = rm;
    const float cm = fmaxf(fmaxf(colp[tid][0], colp[tid][1]),
                           fmaxf(colp[tid][2], colp[tid][3]));
    if (tid < n2) c1 = cm;
  }
  #pragma unroll
  for (int m = 1; m <= 32; m <<= 1) {
    c1 += __shfl_xor(c1, m, 64);
    c2 += __shfl_xor(c2, m, 64);
  }
  if (lane == 0) {
    redbuf[wid]      = c1;
    redbuf[16 + wid] = c2;
  }
  __syncthreads();
  if (tid == 0) {
    float s1s = 0.f, s2s = 0.f;
    #pragma unroll
    for (int i = 0; i < 16; ++i) { s1s += redbuf[i]; s2s += redbuf[16 + i]; }
    const float s1 = s1s / (float)n2;
    const float s2 = s2s / (float)n1;
    feat[bb * NLAYERS + nl] = 2.0f * s1 * s2 / (s1 + s2);
  }
}

// ---------------------------------------------------------------------------
// Kernel 2: BatchNorm1d (batch stats, biased var) + linear head -> out[b]
// ---------------------------------------------------------------------------
__global__ void bs_head(const float* __restrict__ feat, const float* __restrict__ w,
                        const float* __restrict__ bias, float* __restrict__ out) {
  __shared__ float lds[NLAYERS][BATCH];
  const int tid = threadIdx.x;
  const int nl  = tid >> 6;
  const int b   = tid & 63;

  const float x = feat[b * NLAYERS + nl];
  float s = x;
  #pragma unroll
  for (int m = 1; m <= 32; m <<= 1) s += __shfl_xor(s, m, 64);
  const float mean = s / 64.0f;
  const float d = x - mean;
  float v = d * d;
  #pragma unroll
  for (int m = 1; m <= 32; m <<= 1) v += __shfl_xor(v, m, 64);
  const float var = v / 64.0f;
  const float y = d / sqrtf(var + 1e-8f);

  lds[nl][b] = y * w[nl];
  __syncthreads();
  if (tid < 64)
    out[tid] = lds[0][tid] + lds[1][tid] + lds[2][tid] + lds[3][tid] + bias[0];
}

extern "C" void kernel_launch(void* const* d_in, const int* in_sizes, int n_in,
                              void* d_out, int out_size, void* d_ws, size_t ws_size,
                              hipStream_t stream) {
  const float* reps1 = (const float*)d_in[0];
  const float* reps2 = (const float*)d_in[1];
  const int*   len1  = (const int*)d_in[2];
  const int*   len2  = (const int*)d_in[3];
  const float* w     = (const float*)d_in[4];
  const float* bias  = (const float*)d_in[5];
  float* feat = (float*)d_ws;   // 256 floats

  bs_main<<<NLAYERS * BATCH, 1024, 0, stream>>>(reps1, reps2, len1, len2, feat);
  bs_head<<<1, 256, 0, stream>>>(feat, w, bias, (float*)d_out);
}